// Round 2
// baseline (75.813 us; speedup 1.0000x reference)
//
#include <hip/hip_runtime.h>
#include <hip/hip_bf16.h>
#include <stdint.h>

typedef __attribute__((ext_vector_type(8))) short bf16x8;
typedef __attribute__((ext_vector_type(4))) float f32x4;

#define MFMA16(a, b, c) __builtin_amdgcn_mfma_f32_16x16x32_bf16((a), (b), (c), 0, 0, 0)

__device__ __forceinline__ unsigned short f2bf(float f) {
    union { float f; uint32_t u; } v; v.f = f;
    return (unsigned short)((v.u + 0x7fffu + ((v.u >> 16) & 1u)) >> 16);
}

// ---------------------------------------------------------------------------
// prep_h: convert the 8 H tensors (8 blocks x 128 x 128 fp32 each) to bf16,
// transposed within each 128x128 block.
//   Wt[c][blk][i][j] = right_c[blk][j][i]   (stage-A B-operand, [N][K] layout)
//   Lt[c][blk][k][r] = left_c [blk][r][k]   (stage-B A-operand, [M][K] layout)
// ---------------------------------------------------------------------------
__global__ __launch_bounds__(256) void prep_h(
    const float* __restrict__ h2, const float* __restrict__ h3,
    const float* __restrict__ h4, const float* __restrict__ h5,
    const float* __restrict__ h6, const float* __restrict__ h7,
    const float* __restrict__ h8, const float* __restrict__ h9,
    unsigned short* __restrict__ wt, unsigned short* __restrict__ lt)
{
    // c-term tables: right = {hr1,hi1,hi2,hr2,hr3,hi3,hi4,hr4}
    //                left  = {hr1,hi1,hr2,hi2,hr3,hi3,hr4,hi4}
    const float* rmap[8] = {h2, h3, h5, h4, h6, h7, h9, h8};
    const float* lmap[8] = {h2, h3, h4, h5, h6, h7, h8, h9};
    const int wg = blockIdx.x;
    const int which = wg >> 6;       // 0 = Wt, 1 = Lt
    const int c = (wg >> 3) & 7;
    const int blk = wg & 7;
    const float* src = (which ? lmap[c] : rmap[c]) + blk * 16384;
    unsigned short* dst = (which ? lt : wt) + (c * 8 + blk) * 16384;

    __shared__ unsigned short tilebuf[128 * 129];
    const int t = threadIdx.x;
    #pragma unroll 4
    for (int i = 0; i < 64; ++i) {
        int idx = t + 256 * i;            // = r*128 + k, coalesced read
        int r = idx >> 7, k = idx & 127;
        tilebuf[r * 129 + k] = f2bf(src[idx]);
    }
    __syncthreads();
    #pragma unroll 4
    for (int i = 0; i < 64; ++i) {
        int idx = t + 256 * i;            // = k*128 + r, coalesced write
        int k = idx >> 7, r = idx & 127;
        dst[idx] = tilebuf[r * 129 + k];
    }
}

// ---------------------------------------------------------------------------
// prep_x: x (B,16,64,16,64,2) fp32 -> permuted bf16 planes Xre/Xim (B,1024,1024)
// ---------------------------------------------------------------------------
__global__ __launch_bounds__(256) void prep_x(
    const float* __restrict__ x, const int* __restrict__ perm,
    unsigned short* __restrict__ xre, unsigned short* __restrict__ xim)
{
    const int id = blockIdx.x * 256 + threadIdx.x;   // 4*1024*256 total
    const int b = id >> 18;
    const int row = (id >> 8) & 1023;
    const int cg = id & 255;
    const int col0 = cg * 4;
    const int n1 = perm[row >> 6], r1 = row & 63;
    const int n2 = perm[col0 >> 6], r2 = col0 & 63;
    const int src = (((b * 16 + n1) * 64 + r1) * 16 + n2) * 64 + r2;  // float2 units
    const float4* s = (const float4*)(x + src * 2);
    float4 v0 = s[0], v1 = s[1];
    ushort4 re, im;
    re.x = f2bf(v0.x); re.y = f2bf(v0.z); re.z = f2bf(v1.x); re.w = f2bf(v1.z);
    im.x = f2bf(v0.y); im.y = f2bf(v0.w); im.z = f2bf(v1.y); im.w = f2bf(v1.w);
    const int o = id * 4;                 // = (b*1024+row)*1024 + col0
    *(ushort4*)(xre + o) = re;
    *(ushort4*)(xim + o) = im;
}

// ---------------------------------------------------------------------------
// bilin_main: 512 WGs, one per (b,p,q,h) where h = 64-col half of the q tile.
// Output tile 128 rows x 64 cols; 4 waves in 2x2 (wave tile 64x32).
// Per g (re/im X-plane): stage X block -> LDS once; then 4 c-terms:
//   stage A  U = X . W_c[:, half]   (xf from LDS, wf from L2)
//   U^T -> LDS (double-buffered; ONE barrier per c-term)
//   stage B  Y += Lt_c . U          (lf from L2, uf from LDS)
// All LDS access patterns are at the b128 bank floor (stride 136 ushorts).
// h at wg-bit-8 => h-pairs (share X and Lt) land on the same XCD.
// ---------------------------------------------------------------------------
__global__ __launch_bounds__(256, 2) void bilin_main(
    const unsigned short* __restrict__ xre,
    const unsigned short* __restrict__ xim,
    const unsigned short* __restrict__ wt,
    const unsigned short* __restrict__ lt,
    float* __restrict__ out)
{
    const int wg = blockIdx.x;
    const int q = wg & 7, p = (wg >> 3) & 7, b = (wg >> 6) & 3, h = wg >> 8;
    const int tid = threadIdx.x;
    const int lane = tid & 63, wid = tid >> 6;
    const int wm = wid >> 1, wn = wid & 1;
    const int lr = lane & 15, lg = lane >> 4;

    __shared__ __align__(16) unsigned short xlds[128 * 136];
    __shared__ __align__(16) unsigned short utlds[2][64 * 136];

    f32x4 yre[4][2], yim[4][2];
    #pragma unroll
    for (int i = 0; i < 4; ++i)
        #pragma unroll
        for (int j = 0; j < 2; ++j) {
            yre[i][j] = (f32x4){0.f, 0.f, 0.f, 0.f};
            yim[i][j] = (f32x4){0.f, 0.f, 0.f, 0.f};
        }

    // per-WG invariant bases
    const int srow = tid >> 4;            // 0..15 (staging row group)
    const int scol = (tid & 15) * 8;      // 0..120 (staging col, x8 ushorts)
    const unsigned short* lbase0 = lt + p * 16384
                                 + (wm * 64 + lr) * 128 + lg * 8;
    const unsigned short* wbase0 = wt + q * 16384
                                 + (h * 64 + wn * 32 + lr) * 128 + lg * 8;

    for (int g = 0; g < 2; ++g) {
        const unsigned short* xp = g ? xim : xre;
        // ---- stage X block (128x128 bf16) into LDS, [row][k] stride 136
        {
            const unsigned short* gsrc =
                xp + (b * 1024 + p * 128 + srow) * 1024 + q * 128 + scol;
            #pragma unroll
            for (int i = 0; i < 8; ++i) {
                bf16x8 v = *(const bf16x8*)(gsrc + i * 16 * 1024);
                *(bf16x8*)(xlds + (srow + i * 16) * 136 + scol) = v;
            }
        }
        __syncthreads();

        #pragma unroll
        for (int ci = 0; ci < 4; ++ci) {
            const int c = g ? (ci + 2) : ((ci < 2) ? ci : ci + 4);
            // ---- stage A: U = X . W_c (64x32 per wave)
            const unsigned short* wbase = wbase0 + c * 8 * 16384;
            bf16x8 wf[2][4];
            #pragma unroll
            for (int nt = 0; nt < 2; ++nt)
                #pragma unroll
                for (int ks = 0; ks < 4; ++ks)
                    wf[nt][ks] = *(const bf16x8*)(wbase + nt * 2048 + ks * 32);
            f32x4 u[4][2];
            #pragma unroll
            for (int mt = 0; mt < 4; ++mt)
                #pragma unroll
                for (int nt = 0; nt < 2; ++nt)
                    u[mt][nt] = (f32x4){0.f, 0.f, 0.f, 0.f};
            #pragma unroll
            for (int ks = 0; ks < 4; ++ks) {
                bf16x8 xf[4];
                #pragma unroll
                for (int mt = 0; mt < 4; ++mt)
                    xf[mt] = *(const bf16x8*)(xlds + (wm * 64 + mt * 16 + lr) * 136
                                              + ks * 32 + lg * 8);
                #pragma unroll
                for (int mt = 0; mt < 4; ++mt)
                    #pragma unroll
                    for (int nt = 0; nt < 2; ++nt)
                        u[mt][nt] = MFMA16(xf[mt], wf[nt][ks], u[mt][nt]);
            }

            // ---- convert + write U^T to LDS [r][i], double-buffered
            unsigned short* ub = utlds[ci & 1];
            {
                unsigned short* uw = ub + (wn * 32 + lr) * 136
                                   + wm * 64 + lg * 4;
                #pragma unroll
                for (int nt = 0; nt < 2; ++nt)
                    #pragma unroll
                    for (int mt = 0; mt < 4; ++mt) {
                        ushort4 hv;
                        hv.x = f2bf(u[mt][nt][0]);
                        hv.y = f2bf(u[mt][nt][1]);
                        hv.z = f2bf(u[mt][nt][2]);
                        hv.w = f2bf(u[mt][nt][3]);
                        *(ushort4*)(uw + nt * 16 * 136 + mt * 16) = hv;
                    }
            }
            __syncthreads();

            // ---- stage B: Y += Lt_c . U
            bf16x8 uf[2][4];
            #pragma unroll
            for (int nt = 0; nt < 2; ++nt)
                #pragma unroll
                for (int ks = 0; ks < 4; ++ks)
                    uf[nt][ks] = *(const bf16x8*)(ub + (wn * 32 + nt * 16 + lr) * 136
                                                  + ks * 32 + lg * 8);
            const unsigned short* lbase = lbase0 + c * 8 * 16384;
            #pragma unroll
            for (int mt = 0; mt < 4; ++mt) {
                bf16x8 lf[4];
                #pragma unroll
                for (int ks = 0; ks < 4; ++ks)
                    lf[ks] = *(const bf16x8*)(lbase + mt * 2048 + ks * 32);
                #pragma unroll
                for (int ks = 0; ks < 4; ++ks)
                    #pragma unroll
                    for (int nt = 0; nt < 2; ++nt) {
                        if (ci < 2)
                            yre[mt][nt] = MFMA16(lf[ks], uf[nt][ks], yre[mt][nt]);
                        else
                            yim[mt][nt] = MFMA16(lf[ks], uf[nt][ks], yim[mt][nt]);
                    }
            }
            // no end barrier: utlds is double-buffered; the next c's mid-barrier
            // orders this c's reads before the buffer's next overwrite.
        }
        __syncthreads();   // xlds rewrite safety for next g
    }

    // epilogue: interleave (re,im) -> coalesced float2 stores
    float2* o2 = (float2*)out;
    float2* obase = o2 + (b * 1024 + p * 128 + wm * 64 + lg * 4) * 1024
                       + q * 128 + h * 64 + wn * 32 + lr;
    #pragma unroll
    for (int mt = 0; mt < 4; ++mt)
        #pragma unroll
        for (int nt = 0; nt < 2; ++nt)
            #pragma unroll
            for (int j = 0; j < 4; ++j) {
                float2 v;
                v.x = yre[mt][nt][j];
                v.y = yim[mt][nt][j];
                obase[(mt * 16 + j) * 1024 + nt * 16] = v;
            }
}

extern "C" void kernel_launch(void* const* d_in, const int* in_sizes, int n_in,
                              void* d_out, int out_size, void* d_ws, size_t ws_size,
                              hipStream_t stream) {
    const float* x  = (const float*)d_in[0];
    const int* perm = (const int*)d_in[1];
    unsigned short* ws = (unsigned short*)d_ws;
    // workspace layout (ushort units): Xre 4M | Xim 4M | Wt 1M | Lt 1M = 20 MB
    unsigned short* xre = ws;
    unsigned short* xim = ws + 4u * 1024u * 1024u;
    unsigned short* wtp = ws + 8u * 1024u * 1024u;
    unsigned short* ltp = ws + 9u * 1024u * 1024u;

    hipLaunchKernelGGL(prep_h, dim3(128), dim3(256), 0, stream,
        (const float*)d_in[2], (const float*)d_in[3], (const float*)d_in[4],
        (const float*)d_in[5], (const float*)d_in[6], (const float*)d_in[7],
        (const float*)d_in[8], (const float*)d_in[9], wtp, ltp);
    hipLaunchKernelGGL(prep_x, dim3(4096), dim3(256), 0, stream,
        x, perm, xre, xim);
    hipLaunchKernelGGL(bilin_main, dim3(512), dim3(256), 0, stream,
        xre, xim, wtp, ltp, (float*)d_out);
}

// Round 3
// 72.597 us; speedup vs baseline: 1.0443x; 1.0443x over previous
//
#include <hip/hip_runtime.h>
#include <hip/hip_bf16.h>
#include <stdint.h>

typedef __attribute__((ext_vector_type(8))) short bf16x8;
typedef __attribute__((ext_vector_type(4))) float f32x4;

#define MFMA16(a, b, c) __builtin_amdgcn_mfma_f32_16x16x32_bf16((a), (b), (c), 0, 0, 0)

__device__ __forceinline__ unsigned short f2bf_rn(float f) {
    union { __bf16 b; unsigned short u; } v;
    v.b = (__bf16)f;                 // RNE; pairs fuse to v_cvt_pk_bf16_f32
    return v.u;
}

__device__ __forceinline__ ushort4 cvt4(f32x4 v) {
    ushort4 r;
    r.x = f2bf_rn(v[0]); r.y = f2bf_rn(v[1]);
    r.z = f2bf_rn(v[2]); r.w = f2bf_rn(v[3]);
    return r;
}

__device__ __forceinline__ void gload_lds16(const void* g, void* l) {
    __builtin_amdgcn_global_load_lds(
        (const __attribute__((address_space(1))) void*)g,
        (__attribute__((address_space(3))) void*)l, 16, 0, 0);
}

// ---------------------------------------------------------------------------
// prep_h: transpose each 128x128 fp32 block of the 8 H tensors to bf16.
//   ht[j][blk][k][r] = h_j[blk][r][k]    (j = input order hr1,hi1,...,hi4)
// Wt_c = ht[rperm[c]], Lt_c = ht[c] — the same transposed data serves both.
// ---------------------------------------------------------------------------
__global__ __launch_bounds__(256) void prep_h(
    const float* __restrict__ h0, const float* __restrict__ h1,
    const float* __restrict__ h2, const float* __restrict__ h3,
    const float* __restrict__ h4, const float* __restrict__ h5,
    const float* __restrict__ h6, const float* __restrict__ h7,
    unsigned short* __restrict__ ht)
{
    const float* hmap[8] = {h0, h1, h2, h3, h4, h5, h6, h7};
    const int wg = blockIdx.x;        // 64 = j(8) x blk(8)
    const float* src = hmap[wg >> 3] + (wg & 7) * 16384;
    unsigned short* dst = ht + wg * 16384;
    __shared__ unsigned short tile[128 * 129];
    const int t = threadIdx.x;
    #pragma unroll 4
    for (int i = 0; i < 64; ++i) {
        int idx = t + 256 * i, r = idx >> 7, k = idx & 127;
        tile[r * 129 + k] = f2bf_rn(src[idx]);
    }
    __syncthreads();
    #pragma unroll 4
    for (int i = 0; i < 64; ++i) {
        int idx = t + 256 * i, k = idx >> 7, r = idx & 127;
        dst[idx] = tile[r * 129 + k];
    }
}

// ---------------------------------------------------------------------------
// prep_x: x (B,16,64,16,64,2) fp32 -> permuted bf16 planes Xre/Xim (B,1024,1024)
// ---------------------------------------------------------------------------
__global__ __launch_bounds__(256) void prep_x(
    const float* __restrict__ x, const int* __restrict__ perm,
    unsigned short* __restrict__ xre, unsigned short* __restrict__ xim)
{
    const int id = blockIdx.x * 256 + threadIdx.x;   // 4*1024*256 total
    const int b = id >> 18;
    const int row = (id >> 8) & 1023;
    const int col0 = (id & 255) * 4;
    const int n1 = perm[row >> 6], r1 = row & 63;
    const int n2 = perm[col0 >> 6], r2 = col0 & 63;
    const int src = (((b * 16 + n1) * 64 + r1) * 16 + n2) * 64 + r2;  // float2 units
    const float4* s = (const float4*)(x + src * 2);
    float4 v0 = s[0], v1 = s[1];
    ushort4 re, im;
    re.x = f2bf_rn(v0.x); re.y = f2bf_rn(v0.z); re.z = f2bf_rn(v1.x); re.w = f2bf_rn(v1.z);
    im.x = f2bf_rn(v0.y); im.y = f2bf_rn(v0.w); im.z = f2bf_rn(v1.y); im.w = f2bf_rn(v1.w);
    const int o = id * 4;
    *(ushort4*)(xre + o) = re;
    *(ushort4*)(xim + o) = im;
}

// ---------------------------------------------------------------------------
// bilin_main: 512 WGs = (b,p,q,h-half). Output tile 128x64, 4 waves 2x2,
// wave tile 64x32. Per c-term (8 total, ordered by X-plane):
//   early-issue lf/wf-next global batches -> stage A (xf from swizzled LDS,
//   wf prefetched last term) -> cvt_pk U -> swizzled U^T write -> barrier ->
//   stage B from resident lf + swizzled uf.  X staged per-g via
//   global_load_lds with pre-swizzled per-lane source addresses.
// LDS swizzle: element (row, col) at row*128 + (col ^ ((row&7)<<3)).
// ---------------------------------------------------------------------------
__global__ __launch_bounds__(256, 2) void bilin_main(
    const unsigned short* __restrict__ xre,
    const unsigned short* __restrict__ xim,
    const unsigned short* __restrict__ ht,
    float* __restrict__ out)
{
    const int wg = blockIdx.x;
    const int q = wg & 7, p = (wg >> 3) & 7, b = (wg >> 6) & 3, h = wg >> 8;
    const int tid = threadIdx.x;
    const int lane = tid & 63, wid = tid >> 6;
    const int wm = wid >> 1, wn = wid & 1;
    const int lr = lane & 15, lg = lane >> 4;
    const int sw = (lr & 7) << 3;

    __shared__ __align__(16) unsigned short xlds[128 * 128];
    __shared__ __align__(16) unsigned short utlds[2][64 * 128];

    constexpr int cseq[8]  = {0, 1, 6, 7, 2, 3, 4, 5};   // c per cc
    constexpr int rperm[8] = {0, 1, 3, 2, 4, 5, 7, 6};   // Wt tensor index per c

    f32x4 yre[4][2], yim[4][2];
    #pragma unroll
    for (int i = 0; i < 4; ++i)
        #pragma unroll
        for (int j = 0; j < 2; ++j) {
            yre[i][j] = (f32x4){0.f, 0.f, 0.f, 0.f};
            yim[i][j] = (f32x4){0.f, 0.f, 0.f, 0.f};
        }

    const unsigned short* lbase0 = ht + p * 16384 + (wm * 64 + lr) * 128 + lg * 8;
    const unsigned short* wbase0 = ht + q * 16384
                                 + (h * 64 + wn * 32 + lr) * 128 + lg * 8;

    // staging lane geometry (per gload_lds instr: 4 rows x 128 cols)
    const int srow_in = lane >> 4;        // 0..3
    const int scol_lin = (lane & 15) * 8; // linear col slot in LDS

    bf16x8 wf[2][2][4];                   // [parity][nt][ks]
    {   // prefetch wf for cc=0 (c=0, rperm[0]=0)
        #pragma unroll
        for (int nt = 0; nt < 2; ++nt)
            #pragma unroll
            for (int ks = 0; ks < 4; ++ks)
                wf[0][nt][ks] = *(const bf16x8*)(wbase0 + nt * 2048 + ks * 32);
    }

    #pragma unroll
    for (int cc = 0; cc < 8; ++cc) {
        const int g = cc >> 2, ci = cc & 3;
        const int c = cseq[cc];

        if (ci == 0) {
            // ---- stage X plane tile into swizzled LDS (async, no VGPRs)
            const unsigned short* xp = g ? xim : xre;
            const int rbase = wid * 32;
            #pragma unroll
            for (int i = 0; i < 8; ++i) {
                const int grow = rbase + i * 4 + srow_in;
                const int gcol = scol_lin ^ ((grow & 7) << 3);
                const unsigned short* gp =
                    xp + (b * 1024 + p * 128 + grow) * 1024 + q * 128 + gcol;
                gload_lds16(gp, xlds + (rbase + i * 4) * 128);
            }
            __syncthreads();   // compiler drains vmcnt before s_barrier
        }

        // ---- early-issue global batches: lf first half + next wf
        const unsigned short* lbase = lbase0 + c * 131072;
        bf16x8 lf[4][4];
        #pragma unroll
        for (int mt = 0; mt < 2; ++mt)
            #pragma unroll
            for (int ks = 0; ks < 4; ++ks)
                lf[mt][ks] = *(const bf16x8*)(lbase + mt * 2048 + ks * 32);
        if (cc < 7) {
            const unsigned short* wb = wbase0 + rperm[cseq[cc + 1]] * 131072;
            #pragma unroll
            for (int nt = 0; nt < 2; ++nt)
                #pragma unroll
                for (int ks = 0; ks < 4; ++ks)
                    wf[(cc + 1) & 1][nt][ks] =
                        *(const bf16x8*)(wb + nt * 2048 + ks * 32);
        }

        // ---- stage A: U = X . W_c  (64x32 per wave)
        f32x4 u[4][2];
        #pragma unroll
        for (int mt = 0; mt < 4; ++mt)
            #pragma unroll
            for (int nt = 0; nt < 2; ++nt)
                u[mt][nt] = (f32x4){0.f, 0.f, 0.f, 0.f};
        #pragma unroll
        for (int ks = 0; ks < 4; ++ks) {
            bf16x8 xf[4];
            #pragma unroll
            for (int mt = 0; mt < 4; ++mt)
                xf[mt] = *(const bf16x8*)(xlds + (wm * 64 + mt * 16 + lr) * 128
                                          + ((ks * 32 + lg * 8) ^ sw));
            #pragma unroll
            for (int mt = 0; mt < 4; ++mt)
                #pragma unroll
                for (int nt = 0; nt < 2; ++nt)
                    u[mt][nt] = MFMA16(xf[mt], wf[cc & 1][nt][ks], u[mt][nt]);
        }

        // ---- lf second half (drains across the barrier)
        #pragma unroll
        for (int mt = 2; mt < 4; ++mt)
            #pragma unroll
            for (int ks = 0; ks < 4; ++ks)
                lf[mt][ks] = *(const bf16x8*)(lbase + mt * 2048 + ks * 32);

        // ---- cvt + write U^T [i][r] to swizzled LDS (double-buffered)
        unsigned short* ub = utlds[cc & 1];
        #pragma unroll
        for (int nt = 0; nt < 2; ++nt) {
            unsigned short* ur = ub + (wn * 32 + nt * 16 + lr) * 128;
            #pragma unroll
            for (int mt = 0; mt < 4; ++mt) {
                const int col_r = (wm * 64 + mt * 16 + lg * 4) ^ sw;
                *(ushort4*)(ur + col_r) = cvt4(u[mt][nt]);
            }
        }
        __syncthreads();

        // ---- stage B: Y += Lt_c . U
        bf16x8 uf[2][4];
        #pragma unroll
        for (int nt = 0; nt < 2; ++nt)
            #pragma unroll
            for (int ks = 0; ks < 4; ++ks)
                uf[nt][ks] = *(const bf16x8*)(ub + (wn * 32 + nt * 16 + lr) * 128
                                              + ((ks * 32 + lg * 8) ^ sw));
        #pragma unroll
        for (int ks = 0; ks < 4; ++ks)
            #pragma unroll
            for (int mt = 0; mt < 4; ++mt)
                #pragma unroll
                for (int nt = 0; nt < 2; ++nt) {
                    if (ci < 2)
                        yre[mt][nt] = MFMA16(lf[mt][ks], uf[nt][ks], yre[mt][nt]);
                    else
                        yim[mt][nt] = MFMA16(lf[mt][ks], uf[nt][ks], yim[mt][nt]);
                }
        // no end barrier: utlds double-buffered; next c's mid-barrier orders
        // this c's reads before that buffer's next overwrite.  xlds rewrite at
        // the next g is safe: all xf reads precede this c's mid-barrier.
    }

    // ---- epilogue: interleave (re,im) -> coalesced float2 stores
    float2* o2 = (float2*)out;
    float2* obase = o2 + (b * 1024 + p * 128 + wm * 64 + lg * 4) * 1024
                       + q * 128 + h * 64 + wn * 32 + lr;
    #pragma unroll
    for (int mt = 0; mt < 4; ++mt)
        #pragma unroll
        for (int nt = 0; nt < 2; ++nt)
            #pragma unroll
            for (int j = 0; j < 4; ++j) {
                float2 v;
                v.x = yre[mt][nt][j];
                v.y = yim[mt][nt][j];
                obase[(mt * 16 + j) * 1024 + nt * 16] = v;
            }
}

extern "C" void kernel_launch(void* const* d_in, const int* in_sizes, int n_in,
                              void* d_out, int out_size, void* d_ws, size_t ws_size,
                              hipStream_t stream) {
    const float* x  = (const float*)d_in[0];
    const int* perm = (const int*)d_in[1];
    unsigned short* ws = (unsigned short*)d_ws;
    // workspace (ushort units): Xre 4M | Xim 4M | Ht 1M  = 18 MB
    unsigned short* xre = ws;
    unsigned short* xim = ws + 4u * 1024u * 1024u;
    unsigned short* htp = ws + 8u * 1024u * 1024u;

    hipLaunchKernelGGL(prep_h, dim3(64), dim3(256), 0, stream,
        (const float*)d_in[2], (const float*)d_in[3], (const float*)d_in[4],
        (const float*)d_in[5], (const float*)d_in[6], (const float*)d_in[7],
        (const float*)d_in[8], (const float*)d_in[9], htp);
    hipLaunchKernelGGL(prep_x, dim3(4096), dim3(256), 0, stream,
        x, perm, xre, xim);
    hipLaunchKernelGGL(bilin_main, dim3(512), dim3(256), 0, stream,
        xre, xim, htp, (float*)d_out);
}